// Round 9
// baseline (151.066 us; speedup 1.0000x reference)
//
#include <hip/hip_runtime.h>

// T=8192 rows, H=4096 cols, f32 inputs.
// Outputs concat: [ q_dyn (T*H, f32-widened fp8), residual_out (T*H, f32) ]
//
// Two-kernel plan:
//  memset node: zero 4B amax slot in ws (graph-capture-safe, proven R1).
//  k1 (block-per-row): nt-load h,r -> add -> nt-store resid, f64 sumsq
//      (1 barrier), static fp8 quant -> q8 words (normal store, L2/L3-hot
//      for k2), per-row max|q| -> ONE atomicMax(uint bits) into ws.
//      (R8 lesson: per-block blockmax reduce in k2 added 32KB prologue per
//       block = +30% L2 traffic and serialized k2's start. amax is now
//       computed once, atomics hidden under k1's 62us lifetime.)
//  k2 (4096 blocks): load scalar amax, requant q8 -> q_dyn. One q8 word
//      per thread per iter (R7 lesson: per-instruction lane stride must
//      equal access width or nt-stores amplify writes 2.8x).

typedef float v2f __attribute__((ext_vector_type(2)));
typedef float v4f __attribute__((ext_vector_type(4)));

static constexpr int H_DIM = 4096;
#define FP8_MAX_F 448.0f

__device__ __forceinline__ unsigned int quant4(float q0, float q1, float q2, float q3) {
    unsigned int pk = 0;
    pk = __builtin_amdgcn_cvt_pk_fp8_f32(q0, q1, pk, false); // bytes 0,1
    pk = __builtin_amdgcn_cvt_pk_fp8_f32(q2, q3, pk, true);  // bytes 2,3
    return pk;
}

__device__ __forceinline__ float fp8_roundtrip1(float x) {
    unsigned int pk = __builtin_amdgcn_cvt_pk_fp8_f32(x, x, 0, false);
    v2f d = __builtin_amdgcn_cvt_pk_f32_fp8((int)pk, false);
    return d[0];
}

// --- Kernel 1: one block per row ---
__global__ __launch_bounds__(256, 8) void k_rms_quant(
    const float* __restrict__ hs, const float* __restrict__ res,
    const float* __restrict__ wg, const float* __restrict__ scale_p,
    float* __restrict__ resid_out, unsigned int* __restrict__ q8w,
    unsigned int* __restrict__ amax_bits)
{
    __shared__ double sred[4];
    __shared__ float smax[4];

    const int row = blockIdx.x;
    const int t   = threadIdx.x;
    const int lane = t & 63, wv = t >> 6;
    const size_t base  = (size_t)row * H_DIM;   // floats
    const size_t base4 = base >> 2;             // q8 words

    v4f a[4];
    double ss = 0.0;
#pragma unroll
    for (int c = 0; c < 4; ++c) {
        const int col = c * 1024 + t * 4;
        const v4f hv = __builtin_nontemporal_load((const v4f*)(hs + base + col));
        const v4f rv = __builtin_nontemporal_load((const v4f*)(res + base + col));
        const v4f av = hv + rv;
        a[c] = av;
        __builtin_nontemporal_store(av, (v4f*)(resid_out + base + col));
        ss += (double)av.x * (double)av.x + (double)av.y * (double)av.y
            + (double)av.z * (double)av.z + (double)av.w * (double)av.w;
    }

    // Block sum-of-squares: wave shfl reduce, ONE barrier, broadcast sum.
#pragma unroll
    for (int o = 32; o > 0; o >>= 1) ss += __shfl_down(ss, o, 64);
    if (lane == 0) sred[wv] = ss;
    __syncthreads();
    const double tot = sred[0] + sred[1] + sred[2] + sred[3];
    const float inv = (float)(1.0 / sqrt(tot / (double)H_DIM + 1e-6));

    const float s = scale_p[0];
    float lmax = 0.0f;
#pragma unroll
    for (int c = 0; c < 4; ++c) {
        const int col = c * 1024 + t * 4;
        const v4f w4 = *(const v4f*)(wg + col);   // L1/L2-hot across blocks
        const v4f av = a[c];
        float q0 = (av.x * inv) * w4.x / s;
        float q1 = (av.y * inv) * w4.y / s;
        float q2 = (av.z * inv) * w4.z / s;
        float q3 = (av.w * inv) * w4.w / s;
        q0 = fminf(fmaxf(q0, -FP8_MAX_F), FP8_MAX_F);
        q1 = fminf(fmaxf(q1, -FP8_MAX_F), FP8_MAX_F);
        q2 = fminf(fmaxf(q2, -FP8_MAX_F), FP8_MAX_F);
        q3 = fminf(fmaxf(q3, -FP8_MAX_F), FP8_MAX_F);
        q8w[base4 + c * 256 + t] = quant4(q0, q1, q2, q3);  // normal store
        // max|deq| == roundtrip(max|q|): RNE quant monotone & symmetric.
        lmax = fmaxf(lmax, fmaxf(fmaxf(fabsf(q0), fabsf(q1)),
                                 fmaxf(fabsf(q2), fabsf(q3))));
    }

#pragma unroll
    for (int o = 32; o > 0; o >>= 1) lmax = fmaxf(lmax, __shfl_down(lmax, o, 64));
    if (lane == 0) smax[wv] = lmax;
    __syncthreads();
    if (t == 0) {
        const float bm = fmaxf(fmaxf(smax[0], smax[1]), fmaxf(smax[2], smax[3]));
        // Non-negative floats order-compare correctly as uint bit patterns.
        atomicMax(amax_bits, __float_as_uint(bm));
    }
}

// --- Kernel 2: scalar amax load, requant with fully-coalesced stores ---
__global__ __launch_bounds__(256, 8) void k_requant(
    const unsigned int* __restrict__ q8w,
    const unsigned int* __restrict__ amax_bits,
    float* __restrict__ out, size_t nwords)
{
    const float amax_q = __uint_as_float(*amax_bits);
    const float amax   = fp8_roundtrip1(amax_q);      // = max|dequantized|
    const float dscale = fmaxf(amax, 1e-12f) / FP8_MAX_F;

    // One q8 word per thread per iteration: reads 4B/lane (256B/wave
    // contiguous), writes 16B/lane (1KB/wave contiguous full lines).
    size_t i = (size_t)blockIdx.x * 256 + threadIdx.x;
    const size_t stride = (size_t)gridDim.x * 256;
    for (; i < nwords; i += stride) {
        const unsigned int pw = q8w[i];
        const v2f lo = __builtin_amdgcn_cvt_pk_f32_fp8((int)pw, false);
        const v2f hi = __builtin_amdgcn_cvt_pk_f32_fp8((int)pw, true);
        float q0 = lo[0] / dscale, q1 = lo[1] / dscale;
        float q2 = hi[0] / dscale, q3 = hi[1] / dscale;
        q0 = fminf(fmaxf(q0, -FP8_MAX_F), FP8_MAX_F);
        q1 = fminf(fmaxf(q1, -FP8_MAX_F), FP8_MAX_F);
        q2 = fminf(fmaxf(q2, -FP8_MAX_F), FP8_MAX_F);
        q3 = fminf(fmaxf(q3, -FP8_MAX_F), FP8_MAX_F);
        const unsigned int rq = quant4(q0, q1, q2, q3);
        const v2f olo = __builtin_amdgcn_cvt_pk_f32_fp8((int)rq, false);
        const v2f ohi = __builtin_amdgcn_cvt_pk_f32_fp8((int)rq, true);
        v4f ov; ov.x = olo[0]; ov.y = olo[1]; ov.z = ohi[0]; ov.w = ohi[1];
        __builtin_nontemporal_store(ov, (v4f*)(out + i * 4));
    }
}

// --- Fallback kernels (ws too small for q8 intermediate) ---
__global__ __launch_bounds__(256) void k_rms_noq(
    const float* __restrict__ hs, const float* __restrict__ res,
    const float* __restrict__ wg, const float* __restrict__ scale_p,
    float* __restrict__ resid_out, float* __restrict__ inv_arr,
    unsigned int* __restrict__ amax_bits)
{
    __shared__ double sred[4];
    __shared__ float smax[4];
    const int row = blockIdx.x;
    const int t = threadIdx.x;
    const int lane = t & 63, wv = t >> 6;
    const size_t base = (size_t)row * H_DIM;

    v4f a[4];
    double ss = 0.0;
#pragma unroll
    for (int c = 0; c < 4; ++c) {
        const int col = c * 1024 + t * 4;
        const v4f hv = *(const v4f*)(hs + base + col);
        const v4f rv = *(const v4f*)(res + base + col);
        const v4f av = hv + rv;
        a[c] = av;
        *(v4f*)(resid_out + base + col) = av;
        ss += (double)av.x * (double)av.x + (double)av.y * (double)av.y
            + (double)av.z * (double)av.z + (double)av.w * (double)av.w;
    }
#pragma unroll
    for (int o = 32; o > 0; o >>= 1) ss += __shfl_down(ss, o, 64);
    if (lane == 0) sred[wv] = ss;
    __syncthreads();
    const double tot = sred[0] + sred[1] + sred[2] + sred[3];
    const float inv = (float)(1.0 / sqrt(tot / (double)H_DIM + 1e-6));
    if (t == 0) inv_arr[row] = inv;

    const float s = scale_p[0];
    float lmax = 0.0f;
#pragma unroll
    for (int c = 0; c < 4; ++c) {
        const int col = c * 1024 + t * 4;
        const v4f w4 = *(const v4f*)(wg + col);
        const v4f av = a[c];
        float q0 = fminf(fmaxf((av.x * inv) * w4.x / s, -FP8_MAX_F), FP8_MAX_F);
        float q1 = fminf(fmaxf((av.y * inv) * w4.y / s, -FP8_MAX_F), FP8_MAX_F);
        float q2 = fminf(fmaxf((av.z * inv) * w4.z / s, -FP8_MAX_F), FP8_MAX_F);
        float q3 = fminf(fmaxf((av.w * inv) * w4.w / s, -FP8_MAX_F), FP8_MAX_F);
        lmax = fmaxf(lmax, fmaxf(fmaxf(fabsf(q0), fabsf(q1)),
                                 fmaxf(fabsf(q2), fabsf(q3))));
    }
#pragma unroll
    for (int o = 32; o > 0; o >>= 1) lmax = fmaxf(lmax, __shfl_down(lmax, o, 64));
    if (lane == 0) smax[wv] = lmax;
    __syncthreads();
    if (t == 0) {
        const float bm = fmaxf(fmaxf(smax[0], smax[1]), fmaxf(smax[2], smax[3]));
        atomicMax(amax_bits, __float_as_uint(bm));
    }
}

__global__ __launch_bounds__(256) void k_requant_rows(
    const float* __restrict__ resid_out, const float* __restrict__ wg,
    const float* __restrict__ scale_p, const float* __restrict__ inv_arr,
    const unsigned int* __restrict__ amax_bits, float* __restrict__ out)
{
    const int row = blockIdx.x;
    const int t = threadIdx.x;
    const float amax   = fp8_roundtrip1(__uint_as_float(*amax_bits));
    const float dscale = fmaxf(amax, 1e-12f) / FP8_MAX_F;

    const size_t base = (size_t)row * H_DIM;
    const float inv = inv_arr[row];
    const float s = scale_p[0];
#pragma unroll
    for (int c = 0; c < 4; ++c) {
        const int col = c * 1024 + t * 4;
        const v4f av = *(const v4f*)(resid_out + base + col);
        const v4f w4 = *(const v4f*)(wg + col);
        float qs[4] = { (av.x * inv) * w4.x / s, (av.y * inv) * w4.y / s,
                        (av.z * inv) * w4.z / s, (av.w * inv) * w4.w / s };
        v4f ov;
#pragma unroll
        for (int j = 0; j < 4; ++j) {
            float q = fminf(fmaxf(qs[j], -FP8_MAX_F), FP8_MAX_F);
            q = fp8_roundtrip1(q) / dscale;
            q = fminf(fmaxf(q, -FP8_MAX_F), FP8_MAX_F);
            ov[j] = fp8_roundtrip1(q);
        }
        *(v4f*)(out + base + col) = ov;
    }
}

extern "C" void kernel_launch(void* const* d_in, const int* in_sizes, int n_in,
                              void* d_out, int out_size, void* d_ws, size_t ws_size,
                              hipStream_t stream) {
    const float* hs    = (const float*)d_in[0];
    const float* res   = (const float*)d_in[1];
    const float* w     = (const float*)d_in[2];
    const float* scale = (const float*)d_in[3];
    const int Hn = in_sizes[2];           // 4096
    const int Tn = in_sizes[0] / Hn;      // 8192
    const size_t nelem  = (size_t)Tn * Hn;
    const size_t nwords = nelem / 4;

    float* q_dyn_out = (float*)d_out;
    float* resid_out = (float*)d_out + nelem;

    // ws layout: [ amax_bits + pad : 256 B ][ inv: Tn floats ][ q8: nelem bytes ]
    unsigned int* amax_bits = (unsigned int*)d_ws;
    float* inv_arr = (float*)((char*)d_ws + 256);
    unsigned int* q8w = (unsigned int*)((char*)d_ws + 256 + (size_t)Tn * 4);

    // amax slot must be zero every call (ws poisoned 0xAA once, never
    // restored; 0xAAAAAAAA compares as a huge uint). Memset node is
    // graph-capture-safe (proven R1).
    hipMemsetAsync(d_ws, 0, 4, stream);

    if (ws_size >= 256 + (size_t)Tn * 4 + nelem) {
        k_rms_quant<<<Tn, 256, 0, stream>>>(hs, res, w, scale,
                                            resid_out, q8w, amax_bits);
        k_requant<<<4096, 256, 0, stream>>>(q8w, amax_bits,
                                            q_dyn_out, nwords);
    } else {
        k_rms_noq<<<Tn, 256, 0, stream>>>(hs, res, w, scale,
                                          resid_out, inv_arr, amax_bits);
        k_requant_rows<<<Tn, 256, 0, stream>>>(resid_out, w, scale, inv_arr,
                                               amax_bits, q_dyn_out);
    }
}

// Round 10
// 103.487 us; speedup vs baseline: 1.4598x; 1.4598x over previous
//
#include <hip/hip_runtime.h>

// T=8192 rows, H=4096 cols, f32 inputs.
// Outputs concat: [ q_dyn (T*H, f32-widened fp8), residual_out (T*H, f32) ]
//
// Three-kernel plan (NO memset nodes: R9 showed a 4B hipMemsetAsync in-graph
// costs ~50us; NO atomics needed then; NO per-block amax prologue in k2,
// which cost R8 ~128MB of aggregate L2 reads):
//  k1 (block-per-row, ~63us = its 416MB roofline): nt-load h,r -> add ->
//      nt-store resid, f64 sumsq (1 barrier), static fp8 quant -> q8 words
//      (normal store, L2/L3-hot for k2), per-row max|q| -> blockmax[row]
//      (plain store, fully rewritten every call -> poison-safe).
//  k_amax (1 block, ~3us): reduce blockmax (32KB, L2-hot) -> dscale scalar.
//  k2 (4096 blocks): load scalar dscale, requant q8 -> q_dyn. One q8 word
//      per thread per iter (R7 lesson: per-instruction lane stride must
//      equal access width or nt-stores amplify writes 2.8x).

typedef float v2f __attribute__((ext_vector_type(2)));
typedef float v4f __attribute__((ext_vector_type(4)));

static constexpr int H_DIM = 4096;
#define FP8_MAX_F 448.0f

__device__ __forceinline__ unsigned int quant4(float q0, float q1, float q2, float q3) {
    unsigned int pk = 0;
    pk = __builtin_amdgcn_cvt_pk_fp8_f32(q0, q1, pk, false); // bytes 0,1
    pk = __builtin_amdgcn_cvt_pk_fp8_f32(q2, q3, pk, true);  // bytes 2,3
    return pk;
}

__device__ __forceinline__ float fp8_roundtrip1(float x) {
    unsigned int pk = __builtin_amdgcn_cvt_pk_fp8_f32(x, x, 0, false);
    v2f d = __builtin_amdgcn_cvt_pk_f32_fp8((int)pk, false);
    return d[0];
}

// --- Kernel 1: one block per row ---
__global__ __launch_bounds__(256, 8) void k_rms_quant(
    const float* __restrict__ hs, const float* __restrict__ res,
    const float* __restrict__ wg, const float* __restrict__ scale_p,
    float* __restrict__ resid_out, unsigned int* __restrict__ q8w,
    float* __restrict__ blockmax)
{
    __shared__ double sred[4];
    __shared__ float smax[4];

    const int row = blockIdx.x;
    const int t   = threadIdx.x;
    const int lane = t & 63, wv = t >> 6;
    const size_t base  = (size_t)row * H_DIM;   // floats
    const size_t base4 = base >> 2;             // q8 words

    v4f a[4];
    double ss = 0.0;
#pragma unroll
    for (int c = 0; c < 4; ++c) {
        const int col = c * 1024 + t * 4;
        const v4f hv = __builtin_nontemporal_load((const v4f*)(hs + base + col));
        const v4f rv = __builtin_nontemporal_load((const v4f*)(res + base + col));
        const v4f av = hv + rv;
        a[c] = av;
        __builtin_nontemporal_store(av, (v4f*)(resid_out + base + col));
        ss += (double)av.x * (double)av.x + (double)av.y * (double)av.y
            + (double)av.z * (double)av.z + (double)av.w * (double)av.w;
    }

    // Block sum-of-squares: wave shfl reduce, ONE barrier, broadcast sum.
#pragma unroll
    for (int o = 32; o > 0; o >>= 1) ss += __shfl_down(ss, o, 64);
    if (lane == 0) sred[wv] = ss;
    __syncthreads();
    const double tot = sred[0] + sred[1] + sred[2] + sred[3];
    const float inv = (float)(1.0 / sqrt(tot / (double)H_DIM + 1e-6));

    const float s = scale_p[0];
    float lmax = 0.0f;
#pragma unroll
    for (int c = 0; c < 4; ++c) {
        const int col = c * 1024 + t * 4;
        const v4f w4 = *(const v4f*)(wg + col);   // L1/L2-hot across blocks
        const v4f av = a[c];
        float q0 = (av.x * inv) * w4.x / s;
        float q1 = (av.y * inv) * w4.y / s;
        float q2 = (av.z * inv) * w4.z / s;
        float q3 = (av.w * inv) * w4.w / s;
        q0 = fminf(fmaxf(q0, -FP8_MAX_F), FP8_MAX_F);
        q1 = fminf(fmaxf(q1, -FP8_MAX_F), FP8_MAX_F);
        q2 = fminf(fmaxf(q2, -FP8_MAX_F), FP8_MAX_F);
        q3 = fminf(fmaxf(q3, -FP8_MAX_F), FP8_MAX_F);
        q8w[base4 + c * 256 + t] = quant4(q0, q1, q2, q3);  // normal store
        // max|deq| == roundtrip(max|q|): RNE quant monotone & symmetric.
        lmax = fmaxf(lmax, fmaxf(fmaxf(fabsf(q0), fabsf(q1)),
                                 fmaxf(fabsf(q2), fabsf(q3))));
    }

#pragma unroll
    for (int o = 32; o > 0; o >>= 1) lmax = fmaxf(lmax, __shfl_down(lmax, o, 64));
    if (lane == 0) smax[wv] = lmax;
    __syncthreads();
    if (t == 0)
        blockmax[row] = fmaxf(fmaxf(smax[0], smax[1]), fmaxf(smax[2], smax[3]));
}

// --- Kernel amax: one block reduces blockmax -> dscale scalar ---
__global__ __launch_bounds__(256) void k_amax(
    const float* __restrict__ blockmax, int nblk,
    float* __restrict__ dscale_out)
{
    __shared__ float sm[4];
    const int t = threadIdx.x;
    const int lane = t & 63, wv = t >> 6;
    float m = 0.0f;
    for (int i = t * 4; i < nblk; i += 1024) {
        const v4f v = *(const v4f*)(blockmax + i);
        m = fmaxf(fmaxf(m, fmaxf(v.x, v.y)), fmaxf(v.z, v.w));
    }
#pragma unroll
    for (int o = 32; o > 0; o >>= 1) m = fmaxf(m, __shfl_down(m, o, 64));
    if (lane == 0) sm[wv] = m;
    __syncthreads();
    if (t == 0) {
        const float amax_q = fmaxf(fmaxf(sm[0], sm[1]), fmaxf(sm[2], sm[3]));
        const float amax   = fp8_roundtrip1(amax_q);   // = max|dequantized|
        dscale_out[0] = fmaxf(amax, 1e-12f) / FP8_MAX_F;
    }
}

// --- Kernel 2: scalar dscale load, requant with fully-coalesced stores ---
__global__ __launch_bounds__(256, 8) void k_requant(
    const unsigned int* __restrict__ q8w,
    const float* __restrict__ dscale_p,
    float* __restrict__ out, size_t nwords)
{
    const float dscale = dscale_p[0];

    // One q8 word per thread per iteration: reads 4B/lane (256B/wave
    // contiguous), writes 16B/lane (1KB/wave contiguous full lines).
    size_t i = (size_t)blockIdx.x * 256 + threadIdx.x;
    const size_t stride = (size_t)gridDim.x * 256;
    for (; i < nwords; i += stride) {
        const unsigned int pw = q8w[i];
        const v2f lo = __builtin_amdgcn_cvt_pk_f32_fp8((int)pw, false);
        const v2f hi = __builtin_amdgcn_cvt_pk_f32_fp8((int)pw, true);
        float q0 = lo[0] / dscale, q1 = lo[1] / dscale;
        float q2 = hi[0] / dscale, q3 = hi[1] / dscale;
        q0 = fminf(fmaxf(q0, -FP8_MAX_F), FP8_MAX_F);
        q1 = fminf(fmaxf(q1, -FP8_MAX_F), FP8_MAX_F);
        q2 = fminf(fmaxf(q2, -FP8_MAX_F), FP8_MAX_F);
        q3 = fminf(fmaxf(q3, -FP8_MAX_F), FP8_MAX_F);
        const unsigned int rq = quant4(q0, q1, q2, q3);
        const v2f olo = __builtin_amdgcn_cvt_pk_f32_fp8((int)rq, false);
        const v2f ohi = __builtin_amdgcn_cvt_pk_f32_fp8((int)rq, true);
        v4f ov; ov.x = olo[0]; ov.y = olo[1]; ov.z = ohi[0]; ov.w = ohi[1];
        __builtin_nontemporal_store(ov, (v4f*)(out + i * 4));
    }
}

// --- Fallback kernels (ws too small for q8 intermediate) ---
__global__ __launch_bounds__(256) void k_rms_noq(
    const float* __restrict__ hs, const float* __restrict__ res,
    const float* __restrict__ wg, const float* __restrict__ scale_p,
    float* __restrict__ resid_out, float* __restrict__ inv_arr,
    float* __restrict__ blockmax)
{
    __shared__ double sred[4];
    __shared__ float smax[4];
    const int row = blockIdx.x;
    const int t = threadIdx.x;
    const int lane = t & 63, wv = t >> 6;
    const size_t base = (size_t)row * H_DIM;

    v4f a[4];
    double ss = 0.0;
#pragma unroll
    for (int c = 0; c < 4; ++c) {
        const int col = c * 1024 + t * 4;
        const v4f hv = *(const v4f*)(hs + base + col);
        const v4f rv = *(const v4f*)(res + base + col);
        const v4f av = hv + rv;
        a[c] = av;
        *(v4f*)(resid_out + base + col) = av;
        ss += (double)av.x * (double)av.x + (double)av.y * (double)av.y
            + (double)av.z * (double)av.z + (double)av.w * (double)av.w;
    }
#pragma unroll
    for (int o = 32; o > 0; o >>= 1) ss += __shfl_down(ss, o, 64);
    if (lane == 0) sred[wv] = ss;
    __syncthreads();
    const double tot = sred[0] + sred[1] + sred[2] + sred[3];
    const float inv = (float)(1.0 / sqrt(tot / (double)H_DIM + 1e-6));
    if (t == 0) inv_arr[row] = inv;

    const float s = scale_p[0];
    float lmax = 0.0f;
#pragma unroll
    for (int c = 0; c < 4; ++c) {
        const int col = c * 1024 + t * 4;
        const v4f w4 = *(const v4f*)(wg + col);
        const v4f av = a[c];
        float q0 = fminf(fmaxf((av.x * inv) * w4.x / s, -FP8_MAX_F), FP8_MAX_F);
        float q1 = fminf(fmaxf((av.y * inv) * w4.y / s, -FP8_MAX_F), FP8_MAX_F);
        float q2 = fminf(fmaxf((av.z * inv) * w4.z / s, -FP8_MAX_F), FP8_MAX_F);
        float q3 = fminf(fmaxf((av.w * inv) * w4.w / s, -FP8_MAX_F), FP8_MAX_F);
        lmax = fmaxf(lmax, fmaxf(fmaxf(fabsf(q0), fabsf(q1)),
                                 fmaxf(fabsf(q2), fabsf(q3))));
    }
#pragma unroll
    for (int o = 32; o > 0; o >>= 1) lmax = fmaxf(lmax, __shfl_down(lmax, o, 64));
    if (lane == 0) smax[wv] = lmax;
    __syncthreads();
    if (t == 0)
        blockmax[row] = fmaxf(fmaxf(smax[0], smax[1]), fmaxf(smax[2], smax[3]));
}

__global__ __launch_bounds__(256) void k_requant_rows(
    const float* __restrict__ resid_out, const float* __restrict__ wg,
    const float* __restrict__ scale_p, const float* __restrict__ inv_arr,
    const float* __restrict__ dscale_p, float* __restrict__ out)
{
    const int row = blockIdx.x;
    const int t = threadIdx.x;
    const float dscale = dscale_p[0];

    const size_t base = (size_t)row * H_DIM;
    const float inv = inv_arr[row];
    const float s = scale_p[0];
#pragma unroll
    for (int c = 0; c < 4; ++c) {
        const int col = c * 1024 + t * 4;
        const v4f av = *(const v4f*)(resid_out + base + col);
        const v4f w4 = *(const v4f*)(wg + col);
        float qs[4] = { (av.x * inv) * w4.x / s, (av.y * inv) * w4.y / s,
                        (av.z * inv) * w4.z / s, (av.w * inv) * w4.w / s };
        v4f ov;
#pragma unroll
        for (int j = 0; j < 4; ++j) {
            float q = fminf(fmaxf(qs[j], -FP8_MAX_F), FP8_MAX_F);
            q = fp8_roundtrip1(q) / dscale;
            q = fminf(fmaxf(q, -FP8_MAX_F), FP8_MAX_F);
            ov[j] = fp8_roundtrip1(q);
        }
        *(v4f*)(out + base + col) = ov;
    }
}

extern "C" void kernel_launch(void* const* d_in, const int* in_sizes, int n_in,
                              void* d_out, int out_size, void* d_ws, size_t ws_size,
                              hipStream_t stream) {
    const float* hs    = (const float*)d_in[0];
    const float* res   = (const float*)d_in[1];
    const float* w     = (const float*)d_in[2];
    const float* scale = (const float*)d_in[3];
    const int Hn = in_sizes[2];           // 4096
    const int Tn = in_sizes[0] / Hn;      // 8192
    const size_t nelem  = (size_t)Tn * Hn;
    const size_t nwords = nelem / 4;

    float* q_dyn_out = (float*)d_out;
    float* resid_out = (float*)d_out + nelem;

    // ws layout: [ dscale + pad : 256 B ][ blockmax: Tn ][ inv: Tn ][ q8: nelem B ]
    float* dscale_p = (float*)d_ws;
    float* blockmax = (float*)((char*)d_ws + 256);
    float* inv_arr  = blockmax + Tn;
    unsigned int* q8w = (unsigned int*)((char*)d_ws + 256 + (size_t)2 * Tn * 4);

    if (ws_size >= 256 + (size_t)2 * Tn * 4 + nelem) {
        k_rms_quant<<<Tn, 256, 0, stream>>>(hs, res, w, scale,
                                            resid_out, q8w, blockmax);
        k_amax<<<1, 256, 0, stream>>>(blockmax, Tn, dscale_p);
        k_requant<<<4096, 256, 0, stream>>>(q8w, dscale_p, q_dyn_out, nwords);
    } else {
        k_rms_noq<<<Tn, 256, 0, stream>>>(hs, res, w, scale,
                                          resid_out, inv_arr, blockmax);
        k_amax<<<1, 256, 0, stream>>>(blockmax, Tn, dscale_p);
        k_requant_rows<<<Tn, 256, 0, stream>>>(resid_out, w, scale, inv_arr,
                                               dscale_p, q_dyn_out);
    }
}

// Round 11
// 100.777 us; speedup vs baseline: 1.4990x; 1.0269x over previous
//
#include <hip/hip_runtime.h>

// T=8192 rows, H=4096 cols, f32 inputs.
// Outputs concat: [ q_dyn (T*H, f32-widened fp8), residual_out (T*H, f32) ]
//
// Three-kernel plan (no memset nodes - R9: 4B hipMemsetAsync in-graph ~50us;
// no atomics; k_amax separate - R10: merging it into k2 is time-neutral):
//  k1 (block-per-row, ~63us = 96% of fill ceiling on its 416MB):
//      nt-load h,r -> add -> nt-store resid, f64 sumsq (1 barrier),
//      static fp8 quant -> q8 words (normal store -> writer-XCD L2),
//      per-row max|q| -> blockmax[row] (plain store, poison-safe).
//  k_amax (1 block): reduce blockmax -> dscale scalar.
//  k2 (block-per-row, XCD-LOCAL): block r reads row r's q8 from the SAME
//      XCD L2 that k1's block r wrote (both round-robin r%8). 256-entry
//      LDS LUT (one true f32 divide per byte value - exact reference math)
//      replaces per-element divides. Stores: 16B/lane contiguous per
//      instruction (R7 lane-stride==width rule).

typedef float v2f __attribute__((ext_vector_type(2)));
typedef float v4f __attribute__((ext_vector_type(4)));

static constexpr int H_DIM = 4096;
#define FP8_MAX_F 448.0f

__device__ __forceinline__ unsigned int quant4(float q0, float q1, float q2, float q3) {
    unsigned int pk = 0;
    pk = __builtin_amdgcn_cvt_pk_fp8_f32(q0, q1, pk, false); // bytes 0,1
    pk = __builtin_amdgcn_cvt_pk_fp8_f32(q2, q3, pk, true);  // bytes 2,3
    return pk;
}

__device__ __forceinline__ float fp8_roundtrip1(float x) {
    unsigned int pk = __builtin_amdgcn_cvt_pk_fp8_f32(x, x, 0, false);
    v2f d = __builtin_amdgcn_cvt_pk_f32_fp8((int)pk, false);
    return d[0];
}

__device__ __forceinline__ float fp8_byte_to_f32(unsigned int b) {
    v2f d = __builtin_amdgcn_cvt_pk_f32_fp8((int)b, false);
    return d[0];
}

// --- Kernel 1: one block per row (unchanged, at its BW roofline) ---
__global__ __launch_bounds__(256, 8) void k_rms_quant(
    const float* __restrict__ hs, const float* __restrict__ res,
    const float* __restrict__ wg, const float* __restrict__ scale_p,
    float* __restrict__ resid_out, unsigned int* __restrict__ q8w,
    float* __restrict__ blockmax)
{
    __shared__ double sred[4];
    __shared__ float smax[4];

    const int row = blockIdx.x;
    const int t   = threadIdx.x;
    const int lane = t & 63, wv = t >> 6;
    const size_t base  = (size_t)row * H_DIM;   // floats
    const size_t base4 = base >> 2;             // q8 words

    v4f a[4];
    double ss = 0.0;
#pragma unroll
    for (int c = 0; c < 4; ++c) {
        const int col = c * 1024 + t * 4;
        const v4f hv = __builtin_nontemporal_load((const v4f*)(hs + base + col));
        const v4f rv = __builtin_nontemporal_load((const v4f*)(res + base + col));
        const v4f av = hv + rv;
        a[c] = av;
        __builtin_nontemporal_store(av, (v4f*)(resid_out + base + col));
        ss += (double)av.x * (double)av.x + (double)av.y * (double)av.y
            + (double)av.z * (double)av.z + (double)av.w * (double)av.w;
    }

    // Block sum-of-squares: wave shfl reduce, ONE barrier, broadcast sum.
#pragma unroll
    for (int o = 32; o > 0; o >>= 1) ss += __shfl_down(ss, o, 64);
    if (lane == 0) sred[wv] = ss;
    __syncthreads();
    const double tot = sred[0] + sred[1] + sred[2] + sred[3];
    const float inv = (float)(1.0 / sqrt(tot / (double)H_DIM + 1e-6));

    const float s = scale_p[0];
    float lmax = 0.0f;
#pragma unroll
    for (int c = 0; c < 4; ++c) {
        const int col = c * 1024 + t * 4;
        const v4f w4 = *(const v4f*)(wg + col);   // L1/L2-hot across blocks
        const v4f av = a[c];
        float q0 = (av.x * inv) * w4.x / s;
        float q1 = (av.y * inv) * w4.y / s;
        float q2 = (av.z * inv) * w4.z / s;
        float q3 = (av.w * inv) * w4.w / s;
        q0 = fminf(fmaxf(q0, -FP8_MAX_F), FP8_MAX_F);
        q1 = fminf(fmaxf(q1, -FP8_MAX_F), FP8_MAX_F);
        q2 = fminf(fmaxf(q2, -FP8_MAX_F), FP8_MAX_F);
        q3 = fminf(fmaxf(q3, -FP8_MAX_F), FP8_MAX_F);
        q8w[base4 + c * 256 + t] = quant4(q0, q1, q2, q3);  // normal store
        // max|deq| == roundtrip(max|q|): RNE quant monotone & symmetric.
        lmax = fmaxf(lmax, fmaxf(fmaxf(fabsf(q0), fabsf(q1)),
                                 fmaxf(fabsf(q2), fabsf(q3))));
    }

#pragma unroll
    for (int o = 32; o > 0; o >>= 1) lmax = fmaxf(lmax, __shfl_down(lmax, o, 64));
    if (lane == 0) smax[wv] = lmax;
    __syncthreads();
    if (t == 0)
        blockmax[row] = fmaxf(fmaxf(smax[0], smax[1]), fmaxf(smax[2], smax[3]));
}

// --- Kernel amax: one block reduces blockmax -> dscale scalar ---
__global__ __launch_bounds__(256) void k_amax(
    const float* __restrict__ blockmax, int nblk,
    float* __restrict__ dscale_out)
{
    __shared__ float sm[4];
    const int t = threadIdx.x;
    const int lane = t & 63, wv = t >> 6;
    float m = 0.0f;
    for (int i = t * 4; i < nblk; i += 1024) {
        const v4f v = *(const v4f*)(blockmax + i);
        m = fmaxf(fmaxf(m, fmaxf(v.x, v.y)), fmaxf(v.z, v.w));
    }
#pragma unroll
    for (int o = 32; o > 0; o >>= 1) m = fmaxf(m, __shfl_down(m, o, 64));
    if (lane == 0) sm[wv] = m;
    __syncthreads();
    if (t == 0) {
        const float amax_q = fmaxf(fmaxf(sm[0], sm[1]), fmaxf(sm[2], sm[3]));
        const float amax   = fp8_roundtrip1(amax_q);   // = max|dequantized|
        dscale_out[0] = fmaxf(amax, 1e-12f) / FP8_MAX_F;
    }
}

// --- Kernel 2: one block per row (XCD-local q8 read), LUT requant ---
__global__ __launch_bounds__(256, 8) void k_requant(
    const unsigned int* __restrict__ q8w,
    const float* __restrict__ dscale_p,
    float* __restrict__ out)
{
    __shared__ float lut[256];

    // Byte -> final output LUT: exact reference math per byte value
    // (deq = fp8(b); q = deq/dscale true f32 divide; clip; fp8 RNE; widen).
    {
        const float dscale = dscale_p[0];
        const float deq = fp8_byte_to_f32((unsigned int)threadIdx.x);
        float q = deq / dscale;
        q = fminf(fmaxf(q, -FP8_MAX_F), FP8_MAX_F);
        lut[threadIdx.x] = fp8_roundtrip1(q);
    }
    __syncthreads();

    const int row = blockIdx.x;            // same round-robin XCD as k1 writer
    const int t   = threadIdx.x;
    const size_t base4 = (size_t)row * (H_DIM / 4);

#pragma unroll
    for (int c = 0; c < 4; ++c) {
        const unsigned int pw = q8w[base4 + c * 256 + t];
        v4f ov;
        ov.x = lut[pw & 0xff];
        ov.y = lut[(pw >> 8) & 0xff];
        ov.z = lut[(pw >> 16) & 0xff];
        ov.w = lut[pw >> 24];
        __builtin_nontemporal_store(ov,
            (v4f*)(out + (base4 + c * 256 + t) * 4));
    }
}

// --- Fallback kernels (ws too small for q8 intermediate) ---
__global__ __launch_bounds__(256) void k_rms_noq(
    const float* __restrict__ hs, const float* __restrict__ res,
    const float* __restrict__ wg, const float* __restrict__ scale_p,
    float* __restrict__ resid_out, float* __restrict__ inv_arr,
    float* __restrict__ blockmax)
{
    __shared__ double sred[4];
    __shared__ float smax[4];
    const int row = blockIdx.x;
    const int t = threadIdx.x;
    const int lane = t & 63, wv = t >> 6;
    const size_t base = (size_t)row * H_DIM;

    v4f a[4];
    double ss = 0.0;
#pragma unroll
    for (int c = 0; c < 4; ++c) {
        const int col = c * 1024 + t * 4;
        const v4f hv = *(const v4f*)(hs + base + col);
        const v4f rv = *(const v4f*)(res + base + col);
        const v4f av = hv + rv;
        a[c] = av;
        *(v4f*)(resid_out + base + col) = av;
        ss += (double)av.x * (double)av.x + (double)av.y * (double)av.y
            + (double)av.z * (double)av.z + (double)av.w * (double)av.w;
    }
#pragma unroll
    for (int o = 32; o > 0; o >>= 1) ss += __shfl_down(ss, o, 64);
    if (lane == 0) sred[wv] = ss;
    __syncthreads();
    const double tot = sred[0] + sred[1] + sred[2] + sred[3];
    const float inv = (float)(1.0 / sqrt(tot / (double)H_DIM + 1e-6));
    if (t == 0) inv_arr[row] = inv;

    const float s = scale_p[0];
    float lmax = 0.0f;
#pragma unroll
    for (int c = 0; c < 4; ++c) {
        const int col = c * 1024 + t * 4;
        const v4f w4 = *(const v4f*)(wg + col);
        const v4f av = a[c];
        float q0 = fminf(fmaxf((av.x * inv) * w4.x / s, -FP8_MAX_F), FP8_MAX_F);
        float q1 = fminf(fmaxf((av.y * inv) * w4.y / s, -FP8_MAX_F), FP8_MAX_F);
        float q2 = fminf(fmaxf((av.z * inv) * w4.z / s, -FP8_MAX_F), FP8_MAX_F);
        float q3 = fminf(fmaxf((av.w * inv) * w4.w / s, -FP8_MAX_F), FP8_MAX_F);
        lmax = fmaxf(lmax, fmaxf(fmaxf(fabsf(q0), fabsf(q1)),
                                 fmaxf(fabsf(q2), fabsf(q3))));
    }
#pragma unroll
    for (int o = 32; o > 0; o >>= 1) lmax = fmaxf(lmax, __shfl_down(lmax, o, 64));
    if (lane == 0) smax[wv] = lmax;
    __syncthreads();
    if (t == 0)
        blockmax[row] = fmaxf(fmaxf(smax[0], smax[1]), fmaxf(smax[2], smax[3]));
}

__global__ __launch_bounds__(256) void k_requant_rows(
    const float* __restrict__ resid_out, const float* __restrict__ wg,
    const float* __restrict__ scale_p, const float* __restrict__ inv_arr,
    const float* __restrict__ dscale_p, float* __restrict__ out)
{
    const int row = blockIdx.x;
    const int t = threadIdx.x;
    const float dscale = dscale_p[0];

    const size_t base = (size_t)row * H_DIM;
    const float inv = inv_arr[row];
    const float s = scale_p[0];
#pragma unroll
    for (int c = 0; c < 4; ++c) {
        const int col = c * 1024 + t * 4;
        const v4f av = *(const v4f*)(resid_out + base + col);
        const v4f w4 = *(const v4f*)(wg + col);
        float qs[4] = { (av.x * inv) * w4.x / s, (av.y * inv) * w4.y / s,
                        (av.z * inv) * w4.z / s, (av.w * inv) * w4.w / s };
        v4f ov;
#pragma unroll
        for (int j = 0; j < 4; ++j) {
            float q = fminf(fmaxf(qs[j], -FP8_MAX_F), FP8_MAX_F);
            q = fp8_roundtrip1(q) / dscale;
            q = fminf(fmaxf(q, -FP8_MAX_F), FP8_MAX_F);
            ov[j] = fp8_roundtrip1(q);
        }
        *(v4f*)(out + base + col) = ov;
    }
}

extern "C" void kernel_launch(void* const* d_in, const int* in_sizes, int n_in,
                              void* d_out, int out_size, void* d_ws, size_t ws_size,
                              hipStream_t stream) {
    const float* hs    = (const float*)d_in[0];
    const float* res   = (const float*)d_in[1];
    const float* w     = (const float*)d_in[2];
    const float* scale = (const float*)d_in[3];
    const int Hn = in_sizes[2];           // 4096
    const int Tn = in_sizes[0] / Hn;      // 8192
    const size_t nelem  = (size_t)Tn * Hn;

    float* q_dyn_out = (float*)d_out;
    float* resid_out = (float*)d_out + nelem;

    // ws layout: [ dscale + pad : 256 B ][ blockmax: Tn ][ inv: Tn ][ q8: nelem B ]
    float* dscale_p = (float*)d_ws;
    float* blockmax = (float*)((char*)d_ws + 256);
    float* inv_arr  = blockmax + Tn;
    unsigned int* q8w = (unsigned int*)((char*)d_ws + 256 + (size_t)2 * Tn * 4);

    if (ws_size >= 256 + (size_t)2 * Tn * 4 + nelem) {
        k_rms_quant<<<Tn, 256, 0, stream>>>(hs, res, w, scale,
                                            resid_out, q8w, blockmax);
        k_amax<<<1, 256, 0, stream>>>(blockmax, Tn, dscale_p);
        k_requant<<<Tn, 256, 0, stream>>>(q8w, dscale_p, q_dyn_out);
    } else {
        k_rms_noq<<<Tn, 256, 0, stream>>>(hs, res, w, scale,
                                          resid_out, inv_arr, blockmax);
        k_amax<<<1, 256, 0, stream>>>(blockmax, Tn, dscale_p);
        k_requant_rows<<<Tn, 256, 0, stream>>>(resid_out, w, scale, inv_arr,
                                               dscale_p, q_dyn_out);
    }
}